// Round 1
// baseline (229.287 us; speedup 1.0000x reference)
//
#include <hip/hip_runtime.h>
#include <hip/hip_bf16.h>

// SmoothLoss: total = (1/24) * sum over 24 offsets of mean_b,h,w( exp(s*||dx||^2) * ||dy||_1 )
// with x = rgb2ycbcr(input) (bias cancels in differences), y = output, s = -1/(2*10^2).
// Offsets (dh,dw) and (-dh,-dw) contribute identical means -> compute 12, weight x2.

#define B_ 16
#define H_ 512
#define W_ 512
#define HW_ (H_ * W_)
#define CHW_ (3 * HW_)
#define NPIX_ (B_ * HW_)

__global__ void zero_out_kernel(float* p) { p[0] = 0.0f; }

__global__ __launch_bounds__(256) void smooth_loss_kernel(
    const float* __restrict__ in, const float* __restrict__ outp,
    float* __restrict__ result) {
  // half-offset set: one representative per +/- pair
  constexpr int DH[12] = {0, 0, 1, 1, 1, 1, 1, 2, 2, 2, 2, 2};
  constexpr int DW[12] = {1, 2, -2, -1, 0, 1, 2, -2, -1, 0, 1, 2};

  int idx = blockIdx.x * blockDim.x + threadIdx.x;  // pixel index over B*H*W
  float acc = 0.0f;

  if (idx < NPIX_) {
    int b = idx / HW_;
    int p = idx - b * HW_;
    int i = p / W_;
    int j = p - i * W_;

    const float* ib = in + (size_t)b * CHW_ + p;
    const float* ob = outp + (size_t)b * CHW_ + p;

    float r = ib[0], g = ib[HW_], bl = ib[2 * HW_];
    float x0 = 0.257f * r + 0.564f * g + 0.098f * bl;
    float x1 = -0.148f * r - 0.291f * g + 0.439f * bl;
    float x2 = 0.439f * r - 0.368f * g - 0.071f * bl;

    float y0 = ob[0], y1 = ob[HW_], y2 = ob[2 * HW_];

#pragma unroll
    for (int k = 0; k < 12; ++k) {
      const int dh = DH[k];
      const int dw = DW[k];
      // 2 (pair) / (24 offsets * B * h * w)
      const float scale =
          2.0f / (24.0f * (float)B_ * (float)(H_ - dh) *
                  (float)(W_ - (dw < 0 ? -dw : dw)));

      if (i + dh < H_ && j + dw >= 0 && j + dw < W_) {
        const int off = dh * W_ + dw;
        const float* inb = ib + off;
        float nr = inb[0], ng = inb[HW_], nb = inb[2 * HW_];
        float dx0 = x0 - (0.257f * nr + 0.564f * ng + 0.098f * nb);
        float dx1 = x1 - (-0.148f * nr - 0.291f * ng + 0.439f * nb);
        float dx2 = x2 - (0.439f * nr - 0.368f * ng - 0.071f * nb);
        float wgt = __expf(-0.005f * (dx0 * dx0 + dx1 * dx1 + dx2 * dx2));

        const float* onb = ob + off;
        float l1 = fabsf(y0 - onb[0]) + fabsf(y1 - onb[HW_]) +
                   fabsf(y2 - onb[2 * HW_]);
        acc += scale * wgt * l1;
      }
    }
  }

  // wave (64-lane) reduction
#pragma unroll
  for (int o = 32; o > 0; o >>= 1) acc += __shfl_down(acc, o, 64);

  __shared__ float wsum[4];  // 256 threads / 64
  int lane = threadIdx.x & 63;
  int wid = threadIdx.x >> 6;
  if (lane == 0) wsum[wid] = acc;
  __syncthreads();
  if (threadIdx.x == 0) {
    float s = wsum[0] + wsum[1] + wsum[2] + wsum[3];
    atomicAdd(result, s);
  }
}

extern "C" void kernel_launch(void* const* d_in, const int* in_sizes, int n_in,
                              void* d_out, int out_size, void* d_ws, size_t ws_size,
                              hipStream_t stream) {
  const float* in = (const float*)d_in[0];
  const float* outp = (const float*)d_in[1];
  float* res = (float*)d_out;

  zero_out_kernel<<<1, 1, 0, stream>>>(res);

  const int threads = 256;
  const int blocks = (NPIX_ + threads - 1) / threads;  // 16384
  smooth_loss_kernel<<<blocks, threads, 0, stream>>>(in, outp, res);
}

// Round 2
// 72.787 us; speedup vs baseline: 3.1501x; 3.1501x over previous
//
#include <hip/hip_runtime.h>
#include <hip/hip_bf16.h>

// SmoothLoss: total = (1/24) * sum over 24 offsets of mean( exp(s*||dx||^2) * ||dy||_1 )
// x = rgb2ycbcr(input) (bias cancels in diffs), y = output, s = -1/200.
// (dh,dw) and (-dh,-dw) give identical means -> compute 12 offsets, weight 2x.
// Layout: 4 pixels/thread along W, float4 loads, register window of 8 columns,
// ycbcr computed once per loaded column, all offset indexing compile-time.

#define B_ 16
#define H_ 512
#define W_ 512
#define HW_ (H_ * W_)
#define CHW_ (3 * HW_)
#define W4_ (W_ / 4)          // 128 thread-columns per row
#define NT_ (B_ * H_ * W4_)   // total threads

__global__ void zero_out_kernel(float* p) { p[0] = 0.0f; }

__device__ __forceinline__ void load8(const float* __restrict__ rowptr, int j0,
                                      int ls, int rs, float v[8]) {
  // window slots 0..7 = columns j0-2 .. j0+5 (clamped loads; invalid slots
  // are only consumed by masked-out contributions)
  float4 L = *(const float4*)(rowptr + ls);
  float4 M = *(const float4*)(rowptr + j0);
  float4 R = *(const float4*)(rowptr + rs);
  v[0] = L.z; v[1] = L.w;
  v[2] = M.x; v[3] = M.y; v[4] = M.z; v[5] = M.w;
  v[6] = R.x; v[7] = R.y;
}

__device__ __forceinline__ void load_row(const float* __restrict__ inb,
                                         const float* __restrict__ outb,
                                         int row, int j0, int ls, int rs,
                                         float X[3][8], float Y[3][8]) {
  const float* p0 = inb + (size_t)row * W_;
  float r[8], g[8], b[8];
  load8(p0, j0, ls, rs, r);
  load8(p0 + HW_, j0, ls, rs, g);
  load8(p0 + 2 * HW_, j0, ls, rs, b);
#pragma unroll
  for (int c = 0; c < 8; ++c) {
    X[0][c] = 0.257f * r[c] + 0.564f * g[c] + 0.098f * b[c];
    X[1][c] = -0.148f * r[c] - 0.291f * g[c] + 0.439f * b[c];
    X[2][c] = 0.439f * r[c] - 0.368f * g[c] - 0.071f * b[c];
  }
  const float* q0 = outb + (size_t)row * W_;
  load8(q0, j0, ls, rs, Y[0]);
  load8(q0 + HW_, j0, ls, rs, Y[1]);
  load8(q0 + 2 * HW_, j0, ls, rs, Y[2]);
}

template <int DH, int DW>
__device__ __forceinline__ float contrib(int j0, const float OX[3][8],
                                         const float OY[3][8],
                                         const float NX[3][8],
                                         const float NY[3][8]) {
  constexpr int AW = DW < 0 ? -DW : DW;
  const float scale =
      2.0f / (24.0f * (float)B_ * (float)(H_ - DH) * (float)(W_ - AW));
  float s = 0.0f;
#pragma unroll
  for (int p = 0; p < 4; ++p) {
    constexpr int base = 2;
    const int ci = p + base;          // own col slot
    const int ni = p + DW + base;     // neighbor col slot (compile-time per p)
    float dx0 = OX[0][ci] - NX[0][ni];
    float dx1 = OX[1][ci] - NX[1][ni];
    float dx2 = OX[2][ci] - NX[2][ni];
    float wgt = __expf(-0.005f * (dx0 * dx0 + dx1 * dx1 + dx2 * dx2));
    float l1 = fabsf(OY[0][ci] - NY[0][ni]) + fabsf(OY[1][ci] - NY[1][ni]) +
               fabsf(OY[2][ci] - NY[2][ni]);
    int jj = j0 + p + DW;
    s += (jj >= 0 && jj < W_) ? scale * wgt * l1 : 0.0f;
  }
  return s;
}

__global__ __launch_bounds__(256) void smooth_loss_kernel(
    const float* __restrict__ in, const float* __restrict__ outp,
    float* __restrict__ result) {
  int t = blockIdx.x * blockDim.x + threadIdx.x;
  float acc = 0.0f;

  if (t < NT_) {
    int b = t / (H_ * W4_);
    int rem = t - b * (H_ * W4_);
    int i = rem / W4_;
    int jt = rem - i * W4_;
    int j0 = jt * 4;

    const float* inb = in + (size_t)b * CHW_;
    const float* outb = outp + (size_t)b * CHW_;

    const int ls = (j0 >= 4) ? (j0 - 4) : 0;
    const int rs = (j0 + 4 <= W_ - 4) ? (j0 + 4) : (W_ - 4);

    float OX[3][8], OY[3][8];
    float NX[3][8], NY[3][8];

    load_row(inb, outb, i, j0, ls, rs, OX, OY);

    // dh = 0: dw in {1, 2}
    acc += contrib<0, 1>(j0, OX, OY, OX, OY);
    acc += contrib<0, 2>(j0, OX, OY, OX, OY);

    if (i + 1 < H_) {
      load_row(inb, outb, i + 1, j0, ls, rs, NX, NY);
      acc += contrib<1, -2>(j0, OX, OY, NX, NY);
      acc += contrib<1, -1>(j0, OX, OY, NX, NY);
      acc += contrib<1, 0>(j0, OX, OY, NX, NY);
      acc += contrib<1, 1>(j0, OX, OY, NX, NY);
      acc += contrib<1, 2>(j0, OX, OY, NX, NY);
    }
    if (i + 2 < H_) {
      load_row(inb, outb, i + 2, j0, ls, rs, NX, NY);
      acc += contrib<2, -2>(j0, OX, OY, NX, NY);
      acc += contrib<2, -1>(j0, OX, OY, NX, NY);
      acc += contrib<2, 0>(j0, OX, OY, NX, NY);
      acc += contrib<2, 1>(j0, OX, OY, NX, NY);
      acc += contrib<2, 2>(j0, OX, OY, NX, NY);
    }
  }

  // wave (64-lane) reduction
#pragma unroll
  for (int o = 32; o > 0; o >>= 1) acc += __shfl_down(acc, o, 64);

  __shared__ float wsum[4];
  int lane = threadIdx.x & 63;
  int wid = threadIdx.x >> 6;
  if (lane == 0) wsum[wid] = acc;
  __syncthreads();
  if (threadIdx.x == 0) {
    float s = wsum[0] + wsum[1] + wsum[2] + wsum[3];
    atomicAdd(result, s);
  }
}

extern "C" void kernel_launch(void* const* d_in, const int* in_sizes, int n_in,
                              void* d_out, int out_size, void* d_ws, size_t ws_size,
                              hipStream_t stream) {
  const float* in = (const float*)d_in[0];
  const float* outp = (const float*)d_in[1];
  float* res = (float*)d_out;

  zero_out_kernel<<<1, 1, 0, stream>>>(res);

  const int threads = 256;
  const int blocks = (NT_ + threads - 1) / threads;  // 4096
  smooth_loss_kernel<<<blocks, threads, 0, stream>>>(in, outp, res);
}

// Round 3
// 64.763 us; speedup vs baseline: 3.5404x; 1.1239x over previous
//
#include <hip/hip_runtime.h>
#include <hip/hip_bf16.h>

// SmoothLoss: total = (1/24) * sum over 24 offsets of mean( exp(s*||dx||^2) * ||dy||_1 )
// x = rgb2ycbcr(input) (bias cancels in diffs), y = output, s = -1/200.
// (dh,dw) and (-dh,-dw) give identical means -> compute 12 offsets, weight 2x.
// R2: 2 own rows x 4 px per thread; 4-row register window in 4 INDEPENDENT
// buffers so all 72 float4 loads issue up front (no WAR serialization).

#define B_ 16
#define H_ 512
#define W_ 512
#define HW_ (H_ * W_)
#define CHW_ (3 * HW_)
#define W4_ 128               // thread-columns per row
#define NPAIR_ (H_ / 2)       // 256 own-row pairs
#define NT_ (B_ * NPAIR_ * W4_)  // 524288 threads, exactly 2048 blocks of 256

__global__ void zero_out_kernel(float* p) { p[0] = 0.0f; }

__device__ __forceinline__ void load8(const float* __restrict__ rowptr, int j0,
                                      int ls, int rs, float v[8]) {
  // slots 0..7 = cols j0-2 .. j0+5 (clamped loads; invalid slots only feed
  // masked-out contributions)
  float4 L = *(const float4*)(rowptr + ls);
  float4 M = *(const float4*)(rowptr + j0);
  float4 R = *(const float4*)(rowptr + rs);
  v[0] = L.z; v[1] = L.w;
  v[2] = M.x; v[3] = M.y; v[4] = M.z; v[5] = M.w;
  v[6] = R.x; v[7] = R.y;
}

__device__ __forceinline__ void load_row(const float* __restrict__ inb,
                                         const float* __restrict__ outb,
                                         int row, int j0, int ls, int rs,
                                         float X[3][8], float Y[3][8]) {
  const float* p0 = inb + (size_t)row * W_;
  float r[8], g[8], b[8];
  load8(p0, j0, ls, rs, r);
  load8(p0 + HW_, j0, ls, rs, g);
  load8(p0 + 2 * HW_, j0, ls, rs, b);
#pragma unroll
  for (int c = 0; c < 8; ++c) {
    X[0][c] = 0.257f * r[c] + 0.564f * g[c] + 0.098f * b[c];
    X[1][c] = -0.148f * r[c] - 0.291f * g[c] + 0.439f * b[c];
    X[2][c] = 0.439f * r[c] - 0.368f * g[c] - 0.071f * b[c];
  }
  const float* q0 = outb + (size_t)row * W_;
  load8(q0, j0, ls, rs, Y[0]);
  load8(q0 + HW_, j0, ls, rs, Y[1]);
  load8(q0 + 2 * HW_, j0, ls, rs, Y[2]);
}

template <int DH, int DW>
__device__ __forceinline__ float contrib(int j0, const float OX[3][8],
                                         const float OY[3][8],
                                         const float NX[3][8],
                                         const float NY[3][8]) {
  constexpr int AW = DW < 0 ? -DW : DW;
  const float scale =
      2.0f / (24.0f * (float)B_ * (float)(H_ - DH) * (float)(W_ - AW));
  float s = 0.0f;
#pragma unroll
  for (int p = 0; p < 4; ++p) {
    constexpr int base = 2;
    const int ci = p + base;
    const int ni = p + DW + base;
    float dx0 = OX[0][ci] - NX[0][ni];
    float dx1 = OX[1][ci] - NX[1][ni];
    float dx2 = OX[2][ci] - NX[2][ni];
    float wgt = __expf(-0.005f * (dx0 * dx0 + dx1 * dx1 + dx2 * dx2));
    float l1 = fabsf(OY[0][ci] - NY[0][ni]) + fabsf(OY[1][ci] - NY[1][ni]) +
               fabsf(OY[2][ci] - NY[2][ni]);
    int jj = j0 + p + DW;
    s += (jj >= 0 && jj < W_) ? scale * wgt * l1 : 0.0f;
  }
  return s;
}

__global__ __launch_bounds__(256) void smooth_loss_kernel(
    const float* __restrict__ in, const float* __restrict__ outp,
    float* __restrict__ result) {
  int t = blockIdx.x * blockDim.x + threadIdx.x;  // exact grid, no guard
  int b = t / (NPAIR_ * W4_);
  int rem = t - b * (NPAIR_ * W4_);
  int ip = rem / W4_;
  int jt = rem - ip * W4_;
  int i0 = ip * 2;
  int j0 = jt * 4;

  const float* inb = in + (size_t)b * CHW_;
  const float* outb = outp + (size_t)b * CHW_;

  const int ls = (j0 >= 4) ? (j0 - 4) : 0;
  const int rs = (j0 + 4 <= W_ - 4) ? (j0 + 4) : (W_ - 4);

  float X0[3][8], Y0[3][8], X1[3][8], Y1[3][8];
  float X2[3][8], Y2[3][8], X3[3][8], Y3[3][8];

  float acc = 0.0f;

  // rows i0, i0+1 always valid (i0 <= 510)
  load_row(inb, outb, i0, j0, ls, rs, X0, Y0);
  load_row(inb, outb, i0 + 1, j0, ls, rs, X1, Y1);

  if (i0 + 3 < H_) {  // common case: all 4 window rows valid (wave-uniform)
    load_row(inb, outb, i0 + 2, j0, ls, rs, X2, Y2);
    load_row(inb, outb, i0 + 3, j0, ls, rs, X3, Y3);

    // own row i0
    acc += contrib<0, 1>(j0, X0, Y0, X0, Y0);
    acc += contrib<0, 2>(j0, X0, Y0, X0, Y0);
    acc += contrib<1, -2>(j0, X0, Y0, X1, Y1);
    acc += contrib<1, -1>(j0, X0, Y0, X1, Y1);
    acc += contrib<1, 0>(j0, X0, Y0, X1, Y1);
    acc += contrib<1, 1>(j0, X0, Y0, X1, Y1);
    acc += contrib<1, 2>(j0, X0, Y0, X1, Y1);
    acc += contrib<2, -2>(j0, X0, Y0, X2, Y2);
    acc += contrib<2, -1>(j0, X0, Y0, X2, Y2);
    acc += contrib<2, 0>(j0, X0, Y0, X2, Y2);
    acc += contrib<2, 1>(j0, X0, Y0, X2, Y2);
    acc += contrib<2, 2>(j0, X0, Y0, X2, Y2);

    // own row i0+1
    acc += contrib<0, 1>(j0, X1, Y1, X1, Y1);
    acc += contrib<0, 2>(j0, X1, Y1, X1, Y1);
    acc += contrib<1, -2>(j0, X1, Y1, X2, Y2);
    acc += contrib<1, -1>(j0, X1, Y1, X2, Y2);
    acc += contrib<1, 0>(j0, X1, Y1, X2, Y2);
    acc += contrib<1, 1>(j0, X1, Y1, X2, Y2);
    acc += contrib<1, 2>(j0, X1, Y1, X2, Y2);
    acc += contrib<2, -2>(j0, X1, Y1, X3, Y3);
    acc += contrib<2, -1>(j0, X1, Y1, X3, Y3);
    acc += contrib<2, 0>(j0, X1, Y1, X3, Y3);
    acc += contrib<2, 1>(j0, X1, Y1, X3, Y3);
    acc += contrib<2, 2>(j0, X1, Y1, X3, Y3);
  } else {  // i0 == 510: rows 512,513 absent
    // own row 510: dh=0,1 only
    acc += contrib<0, 1>(j0, X0, Y0, X0, Y0);
    acc += contrib<0, 2>(j0, X0, Y0, X0, Y0);
    acc += contrib<1, -2>(j0, X0, Y0, X1, Y1);
    acc += contrib<1, -1>(j0, X0, Y0, X1, Y1);
    acc += contrib<1, 0>(j0, X0, Y0, X1, Y1);
    acc += contrib<1, 1>(j0, X0, Y0, X1, Y1);
    acc += contrib<1, 2>(j0, X0, Y0, X1, Y1);
    // own row 511: dh=0 only
    acc += contrib<0, 1>(j0, X1, Y1, X1, Y1);
    acc += contrib<0, 2>(j0, X1, Y1, X1, Y1);
  }

  // wave (64-lane) reduction
#pragma unroll
  for (int o = 32; o > 0; o >>= 1) acc += __shfl_down(acc, o, 64);

  __shared__ float wsum[4];
  int lane = threadIdx.x & 63;
  int wid = threadIdx.x >> 6;
  if (lane == 0) wsum[wid] = acc;
  __syncthreads();
  if (threadIdx.x == 0) {
    float s = wsum[0] + wsum[1] + wsum[2] + wsum[3];
    atomicAdd(result, s);
  }
}

extern "C" void kernel_launch(void* const* d_in, const int* in_sizes, int n_in,
                              void* d_out, int out_size, void* d_ws, size_t ws_size,
                              hipStream_t stream) {
  const float* in = (const float*)d_in[0];
  const float* outp = (const float*)d_in[1];
  float* res = (float*)d_out;

  zero_out_kernel<<<1, 1, 0, stream>>>(res);

  const int threads = 256;
  const int blocks = NT_ / threads;  // 2048
  smooth_loss_kernel<<<blocks, threads, 0, stream>>>(in, outp, res);
}